// Round 2
// baseline (134.016 us; speedup 1.0000x reference)
//
#include <hip/hip_runtime.h>
#include <math.h>

#define B_    16
#define N_    128
#define F_IN_ 8
#define S_    8
#define F_OUT_ 64
#define KN_HID_ 32
#define FC_HID_ 32

// workspace layout (float offsets)
//  w2x  : [B*N][KN_HID][F_OUT] = 2048*32*64 = 4194304
//  b2x  : [B*N][F_OUT]         = 131072
//  xroot: [B*N][F_OUT]         = 131072
//  nodes: [B*N][F_OUT]         = 131072   (post-relu node features, pooled by k3)
#define W2X_OFF   0
#define B2X_OFF   4194304
#define XROOT_OFF (B2X_OFF + 131072)
#define NODE_OFF  (XROOT_OFF + 131072)

// ---------------------------------------------------------------------------
// k1: per source node (b,i) precompute
//   W2x[k,o]  = sum_f X[b,i,f] * kn_w2[k, f*64+o]       -> ws[W2X_OFF + bi*2048]
//   b2x[o]    = sum_f X[b,i,f] * kn_b2[f*64+o]
//   xroot[o]  = sum_f X[b,i,f] * root_w[f,o]
// blockIdx = i*16 + b  => blocks of batch b land on XCD b%8 (same as k2 reader)
// ---------------------------------------------------------------------------
__global__ __launch_bounds__(256) void k1_precompute(
    const float* __restrict__ X, const float* __restrict__ kn_w2,
    const float* __restrict__ kn_b2, const float* __restrict__ root_w,
    float* __restrict__ ws)
{
    const int b  = blockIdx.x & 15;
    const int i  = blockIdx.x >> 4;
    const int bi = b * N_ + i;
    const int t  = threadIdx.x;

    float x[F_IN_];
#pragma unroll
    for (int f = 0; f < F_IN_; ++f) x[f] = X[bi * F_IN_ + f];

    const int o     = t & 63;
    const int kbase = t >> 6;           // 0..3
    float* w2x = ws + W2X_OFF + (size_t)bi * (KN_HID_ * F_OUT_);
#pragma unroll
    for (int j = 0; j < 8; ++j) {
        const int k = kbase + 4 * j;    // covers 0..31
        float acc = 0.f;
#pragma unroll
        for (int f = 0; f < F_IN_; ++f)
            acc += x[f] * kn_w2[k * (F_IN_ * F_OUT_) + f * F_OUT_ + o];
        w2x[k * F_OUT_ + o] = acc;      // coalesced across lanes (o contiguous)
    }

    if (t < F_OUT_) {
        float accb = 0.f, accr = 0.f;
#pragma unroll
        for (int f = 0; f < F_IN_; ++f) {
            accb += x[f] * kn_b2[f * F_OUT_ + t];
            accr += x[f] * root_w[f * F_OUT_ + t];
        }
        ws[B2X_OFF + bi * F_OUT_ + t]   = accb;
        ws[XROOT_OFF + bi * F_OUT_ + t] = accr;
    }
}

// ---------------------------------------------------------------------------
// k2: one 256-thread block (4 waves) per destination node (b,n). lane = o.
// Active edges found by ballot over the A row, processed round-robin across
// the 4 waves. h is computed redundantly per lane (lane&31) and broadcast
// with __shfl — no __syncthreads in the edge loop.
//   node[o] = relu( sum_{i active} (sum_k h[k]*W2x[b,i,k,o] + b2x[b,i,o])
//                   + xroot[b,n,o] + conv_b[o] )
// blockIdx = n*16 + b  => batch b pinned to XCD b%8 (W2x slice stays in L2)
// ---------------------------------------------------------------------------
__global__ __launch_bounds__(256, 8) void k2_edges(
    const float* __restrict__ A, const float* __restrict__ E,
    const float* __restrict__ kn_w1, const float* __restrict__ kn_b1,
    const float* __restrict__ conv_b, float* __restrict__ ws)
{
    const int b    = blockIdx.x & 15;
    const int n    = blockIdx.x >> 4;
    const int bn   = b * N_ + n;
    const int lane = threadIdx.x & 63;
    const int wave = threadIdx.x >> 6;
    const int j    = lane & 31;         // h index this lane computes

    // per-lane slice of kn_w1 (column j), preloaded
    float w1j[S_];
#pragma unroll
    for (int s = 0; s < S_; ++s) w1j[s] = kn_w1[s * KN_HID_ + j];
    const float b1j = kn_b1[j];

    // adjacency row -> ballot masks (identical in all 4 waves)
    const float a0 = A[(size_t)bn * N_ + lane];
    const float a1 = A[(size_t)bn * N_ + 64 + lane];
    const unsigned long long m0 = __ballot(a0 != 0.f);
    const unsigned long long m1 = __ballot(a1 != 0.f);

    const float* __restrict__ w2x_b = ws + W2X_OFF + (size_t)b * (N_ * KN_HID_ * F_OUT_);
    const float* __restrict__ b2x_b = ws + B2X_OFF + (size_t)b * (N_ * F_OUT_);
    const float* __restrict__ Ebn   = E + (size_t)bn * N_ * S_;

    float acc = 0.f;
    int cnt = 0;
#pragma unroll
    for (int half = 0; half < 2; ++half) {
        unsigned long long m = half ? m1 : m0;
        while (m) {
            const int i = __builtin_ctzll(m) + half * 64;
            m &= m - 1;
            if ((cnt++ & 3) != wave) continue;   // wave-uniform

            // E row broadcast: lanes 0..7 hold e[0..7]
            const float ev = Ebn[i * S_ + (lane & 7)];
            float hv = b1j;
#pragma unroll
            for (int s = 0; s < S_; ++s)
                hv += __shfl(ev, s) * w1j[s];
            hv = hv > 0.f ? hv : 0.f;            // h[j], j = lane&31

            const float* __restrict__ w = w2x_b + (size_t)i * (KN_HID_ * F_OUT_) + lane;
            float e2 = b2x_b[i * F_OUT_ + lane];
#pragma unroll
            for (int k = 0; k < KN_HID_; ++k)
                e2 += __shfl(hv, k) * w[k * F_OUT_];
            acc += e2;                           // A value is exactly 1.0
        }
    }

    __shared__ float part[4][F_OUT_];
    part[wave][lane] = acc;
    __syncthreads();

    if (wave == 0) {
        float r = part[0][lane] + part[1][lane] + part[2][lane] + part[3][lane];
        r += ws[XROOT_OFF + (size_t)bn * F_OUT_ + lane] + conv_b[lane];
        r = r > 0.f ? r : 0.f;
        ws[NODE_OFF + (size_t)bn * F_OUT_ + lane] = r;
    }
}

// ---------------------------------------------------------------------------
// k3: pooling + head. One 256-thread block per batch element.
// ---------------------------------------------------------------------------
__global__ __launch_bounds__(256) void k3_head(
    const float* __restrict__ fc_w, const float* __restrict__ fc_b,
    const float* __restrict__ out_w, const float* __restrict__ out_b,
    const float* __restrict__ ws, float* __restrict__ out)
{
    const int b = blockIdx.x;
    const int t = threadIdx.x;
    const int o = t & 63;
    const int g = t >> 6;

    float p = 0.f;
    for (int n = g; n < N_; n += 4)
        p += ws[NODE_OFF + (size_t)(b * N_ + n) * F_OUT_ + o];

    __shared__ float red[4][F_OUT_];
    __shared__ float pm[F_OUT_];
    __shared__ float y[FC_HID_];
    red[g][o] = p;
    __syncthreads();

    if (t < F_OUT_)
        pm[t] = (red[0][t] + red[1][t] + red[2][t] + red[3][t]) * (1.0f / (float)N_);
    __syncthreads();

    if (t < FC_HID_) {
        float v = fc_b[t];
#pragma unroll
        for (int o2 = 0; o2 < F_OUT_; ++o2) v += pm[o2] * fc_w[o2 * FC_HID_ + t];
        y[t] = v > 0.f ? v : 0.f;
    }
    __syncthreads();

    if (t == 0) {
        float z = out_b[0];
#pragma unroll
        for (int q = 0; q < FC_HID_; ++q) z += y[q] * out_w[q];
        out[b] = 1.f / (1.f + expf(-z));
    }
}

extern "C" void kernel_launch(void* const* d_in, const int* in_sizes, int n_in,
                              void* d_out, int out_size, void* d_ws, size_t ws_size,
                              hipStream_t stream)
{
    const float* A      = (const float*)d_in[0];
    const float* X      = (const float*)d_in[1];
    const float* E      = (const float*)d_in[2];
    const float* kn_w1  = (const float*)d_in[3];
    const float* kn_b1  = (const float*)d_in[4];
    const float* kn_w2  = (const float*)d_in[5];
    const float* kn_b2  = (const float*)d_in[6];
    const float* root_w = (const float*)d_in[7];
    const float* conv_b = (const float*)d_in[8];
    const float* fc_w   = (const float*)d_in[9];
    const float* fc_b   = (const float*)d_in[10];
    const float* out_w  = (const float*)d_in[11];
    const float* out_b  = (const float*)d_in[12];

    float* ws  = (float*)d_ws;
    float* out = (float*)d_out;

    k1_precompute<<<B_ * N_, 256, 0, stream>>>(X, kn_w2, kn_b2, root_w, ws);
    k2_edges<<<B_ * N_, 256, 0, stream>>>(A, E, kn_w1, kn_b1, conv_b, ws);
    k3_head<<<B_, 256, 0, stream>>>(fc_w, fc_b, out_w, out_b, ws, out);
}

// Round 3
// 106.466 us; speedup vs baseline: 1.2588x; 1.2588x over previous
//
#include <hip/hip_runtime.h>
#include <math.h>

#define B_    16
#define N_    128
#define F_IN_ 8
#define S_    8
#define F_OUT_ 64
#define KN_HID_ 32
#define FC_HID_ 32

// workspace layout (float offsets)
//  nodes: [B*N][F_OUT] = 131072  (post-relu node features, pooled by k3)
#define NODE_OFF  0

// ---------------------------------------------------------------------------
// k2: fused ECCConv via the T-factorization.
//   T[k,f]  = sum_{i active} h[b,n,i,k] * X[b,i,f]   (32x8 per node, regs)
//   T[32,f] = sum_{i active} X[b,i,f]                (bias row)
//   node[o] = relu( sum_{kf} T[kf]*w2ext[kf,o] + X[b,n]@root_w + conv_b )
// where w2ext = concat(kn_w2 rows (k,f)->kf, kn_b2 rows) — shared, L1/L2-hot.
// Grid: 256 blocks x 256 thr; block = 8 nodes (same batch), wave = 2 nodes.
// ---------------------------------------------------------------------------
__global__ __launch_bounds__(256) void k2_fused(
    const float* __restrict__ A, const float* __restrict__ X,
    const float* __restrict__ E,
    const float* __restrict__ kn_w1, const float* __restrict__ kn_b1,
    const float* __restrict__ kn_w2, const float* __restrict__ kn_b2,
    const float* __restrict__ root_w, const float* __restrict__ conv_b,
    float* __restrict__ ws)
{
    __shared__ float Xlds[N_ * F_IN_];          // 4 KB, whole X row of batch b
    __shared__ float Elds[4][2][N_ * S_];       // 32 KB, E rows (wave, node)
    __shared__ float Tlds[4][2][264];           // 8.4 KB (264*4=1056, 16B-mult)

    const int t    = threadIdx.x;
    const int lane = t & 63;
    const int wave = t >> 6;
    const int h2   = lane >> 5;                 // f-group: 0 -> f 0..3, 1 -> 4..7
    const int j    = lane & 31;                 // h index this lane owns
    const int b    = blockIdx.x >> 4;           // 16 blocks per batch
    const int bn0  = blockIdx.x * 8 + wave * 2; // first of this wave's 2 nodes

    // stage X[b,:,:] (4 KB) once per block
    const float4* __restrict__ Xg4 = (const float4*)(X + b * N_ * F_IN_);
    ((float4*)Xlds)[t] = Xg4[t];

    // per-lane column j of kn_w1
    float w1j[S_];
#pragma unroll
    for (int s = 0; s < S_; ++s) w1j[s] = kn_w1[s * KN_HID_ + j];
    const float b1j = kn_b1[j];

    // stage both nodes' E rows + A rows (all loads independent, one latency)
    float4 e4[2][4];
    float a0[2], a1[2];
#pragma unroll
    for (int nn = 0; nn < 2; ++nn) {
        const int bn = bn0 + nn;
        const float4* __restrict__ Eg4 = (const float4*)(E + (size_t)bn * N_ * S_);
#pragma unroll
        for (int q = 0; q < 4; ++q) e4[nn][q] = Eg4[q * 64 + lane];
        a0[nn] = A[(size_t)bn * N_ + lane];
        a1[nn] = A[(size_t)bn * N_ + 64 + lane];
    }
#pragma unroll
    for (int nn = 0; nn < 2; ++nn) {
        float4* __restrict__ El4 = (float4*)Elds[wave][nn];
#pragma unroll
        for (int q = 0; q < 4; ++q) El4[q * 64 + lane] = e4[nn][q];
    }
    __syncthreads();   // only needed for Xlds cross-wave visibility

    const float4* __restrict__ Xl4 = (const float4*)Xlds;

    // ---- edge phase: accumulate T in registers (A values are exactly 1.0) --
#pragma unroll
    for (int nn = 0; nn < 2; ++nn) {
        const unsigned long long m0 = __ballot(a0[nn] != 0.f);
        const unsigned long long m1 = __ballot(a1[nn] != 0.f);
        const float* __restrict__ Eln = Elds[wave][nn];

        float T[4] = {0.f, 0.f, 0.f, 0.f};
        float xs[4] = {0.f, 0.f, 0.f, 0.f};

#pragma unroll
        for (int half = 0; half < 2; ++half) {
            unsigned long long m = half ? m1 : m0;
            while (m) {
                const int i = __builtin_ctzll(m) + half * 64;
                m &= m - 1;

                const float ev = Eln[i * S_ + (lane & 7)];
                float hv = b1j;
#pragma unroll
                for (int s = 0; s < S_; ++s)
                    hv += __shfl(ev, s) * w1j[s];
                hv = hv > 0.f ? hv : 0.f;        // h[j]

                const float4 xf = Xl4[i * 2 + h2]; // X[b,i,4*h2..4*h2+3], bcast
                T[0] += hv * xf.x;  T[1] += hv * xf.y;
                T[2] += hv * xf.z;  T[3] += hv * xf.w;
                xs[0] += xf.x; xs[1] += xf.y; xs[2] += xf.z; xs[3] += xf.w;
            }
        }

        // T[k,f] -> LDS at kf = k*8+f; bias row kf = 256..263
        float4* __restrict__ Tl4 = (float4*)Tlds[wave][nn];
        Tl4[j * 2 + h2] = make_float4(T[0], T[1], T[2], T[3]);
        if (j == 0)
            Tl4[64 + h2] = make_float4(xs[0], xs[1], xs[2], xs[3]);
    }
    // same-wave LDS write->read: compiler inserts lgkmcnt waits, no barrier

    // ---- contraction: acc[o] = sum_kf T[kf] * w2ext[kf*64+o] ---------------
    // kn_w2 flat layout [k][f*64+o] == [kf*64+o]; kn_b2 is rows 256..263.
    const float* __restrict__ T0 = Tlds[wave][0];
    const float* __restrict__ T1 = Tlds[wave][1];
    float acc0 = 0.f, acc1 = 0.f;
#pragma unroll 8
    for (int kf = 0; kf < 256; ++kf) {
        const float w = kn_w2[kf * F_OUT_ + lane];   // coalesced, L1-hot
        acc0 += T0[kf] * w;
        acc1 += T1[kf] * w;
    }
#pragma unroll
    for (int f = 0; f < F_IN_; ++f) {
        const float w = kn_b2[f * F_OUT_ + lane];
        acc0 += T0[256 + f] * w;
        acc1 += T1[256 + f] * w;
    }

    // ---- epilogue: + X[b,n]@root_w + conv_b, relu, store node feature ------
    const float cb = conv_b[lane];
#pragma unroll
    for (int nn = 0; nn < 2; ++nn) {
        const int bn = bn0 + nn;
        const int n  = bn & (N_ - 1);
        float r = (nn == 0) ? acc0 : acc1;
#pragma unroll
        for (int f = 0; f < F_IN_; ++f)
            r += Xlds[n * F_IN_ + f] * root_w[f * F_OUT_ + lane];
        r += cb;
        r = r > 0.f ? r : 0.f;
        ws[NODE_OFF + (size_t)bn * F_OUT_ + lane] = r;
    }
}

// ---------------------------------------------------------------------------
// k3: pooling + head. One 256-thread block per batch element.
// ---------------------------------------------------------------------------
__global__ __launch_bounds__(256) void k3_head(
    const float* __restrict__ fc_w, const float* __restrict__ fc_b,
    const float* __restrict__ out_w, const float* __restrict__ out_b,
    const float* __restrict__ ws, float* __restrict__ out)
{
    const int b = blockIdx.x;
    const int t = threadIdx.x;
    const int o = t & 63;
    const int g = t >> 6;

    float p = 0.f;
    for (int n = g; n < N_; n += 4)
        p += ws[NODE_OFF + (size_t)(b * N_ + n) * F_OUT_ + o];

    __shared__ float red[4][F_OUT_];
    __shared__ float pm[F_OUT_];
    __shared__ float y[FC_HID_];
    red[g][o] = p;
    __syncthreads();

    if (t < F_OUT_)
        pm[t] = (red[0][t] + red[1][t] + red[2][t] + red[3][t]) * (1.0f / (float)N_);
    __syncthreads();

    if (t < FC_HID_) {
        float v = fc_b[t];
#pragma unroll
        for (int o2 = 0; o2 < F_OUT_; ++o2) v += pm[o2] * fc_w[o2 * FC_HID_ + t];
        y[t] = v > 0.f ? v : 0.f;
    }
    __syncthreads();

    if (t == 0) {
        float z = out_b[0];
#pragma unroll
        for (int q = 0; q < FC_HID_; ++q) z += y[q] * out_w[q];
        out[b] = 1.f / (1.f + expf(-z));
    }
}

extern "C" void kernel_launch(void* const* d_in, const int* in_sizes, int n_in,
                              void* d_out, int out_size, void* d_ws, size_t ws_size,
                              hipStream_t stream)
{
    const float* A      = (const float*)d_in[0];
    const float* X      = (const float*)d_in[1];
    const float* E      = (const float*)d_in[2];
    const float* kn_w1  = (const float*)d_in[3];
    const float* kn_b1  = (const float*)d_in[4];
    const float* kn_w2  = (const float*)d_in[5];
    const float* kn_b2  = (const float*)d_in[6];
    const float* root_w = (const float*)d_in[7];
    const float* conv_b = (const float*)d_in[8];
    const float* fc_w   = (const float*)d_in[9];
    const float* fc_b   = (const float*)d_in[10];
    const float* out_w  = (const float*)d_in[11];
    const float* out_b  = (const float*)d_in[12];

    float* ws  = (float*)d_ws;
    float* out = (float*)d_out;

    k2_fused<<<B_ * N_ / 8, 256, 0, stream>>>(A, X, E, kn_w1, kn_b1,
                                              kn_w2, kn_b2, root_w, conv_b, ws);
    k3_head<<<B_, 256, 0, stream>>>(fc_w, fc_b, out_w, out_b, ws, out);
}